// Round 16
// baseline (7912.975 us; speedup 1.0000x reference)
//
#include <hip/hip_runtime.h>
#include <cstdint>
#include <cstddef>

// LSTM_Generator: 3-layer LSTM (H=100) + tanh projection. B=512, T=512.
//
// R15: cross-layer WAVEFRONT PIPELINE. R14's null result killed the
// store-drain theory; per-step ~4000cyc is irreducible latency for the
// 32-block MFMA recurrence. The lever is the 1536 SEQUENTIAL steps: layer
// l step t only needs layer l-1 step t. Fuse all 3 layers into ONE kernel
// (96 blocks co-resident), pipelined via global ring buffers + agent-scope
// acquire/release counters:
//   - producers (layer 0,1) publish h(t) fp16 TRANSPOSED [br][104] into a
//     16-slot ring; release prod_cnt after __syncthreads (vmcnt-drained).
//   - consumers (layer 1,2) global-load x B-fragments directly from the
//     ring (no LDS staging); x(t+1) loads issued right after x(t)'s last
//     use -> full-step latency hiding; backpressure via cons_cnt.
//   - the old xwp GEMM folds in as a 3rd independent MFMA chain (ax),
//     single-fp16 x = exactly the validated xwp numerics (absmax 1.22e-4).
// Sequential steps: 1536 -> 512 + ~4 fill. ws = 108.9MB < 119MB proven.

#define HH 100
#define G4 400
#define NB 512
#define NT 512
#define NBG 32
#define NTILE 25
#define KP 128    // f16 per LDS h row (XOR-swizzled)
#define XROW 104  // f16 per hpipeT row (16B-aligned; overreads hit live ws)
#define RW 16     // ring depth (steps)

typedef _Float16 f16;
typedef _Float16 f16x8 __attribute__((ext_vector_type(8)));
typedef float f32x4 __attribute__((ext_vector_type(4)));

__device__ __forceinline__ float sigm(float x) { return 1.0f / (1.0f + __expf(-x)); }
__device__ __forceinline__ float tanh_(float x) { return 1.0f - 2.0f / (__expf(2.0f * x) + 1.0f); }

#define PIN22 __attribute__((amdgpu_flat_work_group_size(512, 512), \
                             amdgpu_waves_per_eu(2, 2)))

__device__ __forceinline__ void spin_ge(const uint32_t* p, uint32_t v) {
  while (__hip_atomic_load(p, __ATOMIC_ACQUIRE, __HIP_MEMORY_SCOPE_AGENT) < v)
    __builtin_amdgcn_s_sleep(2);
}
__device__ __forceinline__ void rel_store(uint32_t* p, uint32_t v) {
  __hip_atomic_store(p, v, __ATOMIC_RELEASE, __HIP_MEMORY_SCOPE_AGENT);
}

// swizzled f16 index in a [16][KP] LDS buffer
__device__ __forceinline__ int hswz(int b2, int u) {
  return b2 * KP + ((((u >> 3) ^ (b2 & 7)) << 3) | (u & 7));
}
__device__ __forceinline__ int bswz(int b2, int j) {
  return b2 * KP + ((j ^ (b2 & 7)) << 3);
}

// ---------------- init: zero ring + counters ----------------
__global__ __launch_bounds__(256) void initk(uint32_t* __restrict__ ring_u32,
                                             uint32_t* __restrict__ cnts) {
  const int n_ring = 2 * NBG * RW * 16 * XROW / 2;   // f16 pairs as u32
  for (int i = blockIdx.x * 256 + threadIdx.x; i < n_ring; i += gridDim.x * 256)
    ring_u32[i] = 0u;
  int i = blockIdx.x * 256 + threadIdx.x;
  if (i < 2048) cnts[i] = 0u;
}

// ---------------- weight prep (verbatim R10/R12, validated) ----------------
__global__ __launch_bounds__(256) void wprep(
    const float* __restrict__ Whh0, const float* __restrict__ Whh1,
    const float* __restrict__ Whh2, const float* __restrict__ Wih1,
    const float* __restrict__ Wih2, const float* __restrict__ b1,
    const float* __restrict__ b2, const float* __restrict__ Wih0,
    const float* __restrict__ b0,
    f16* __restrict__ wfA, f16* __restrict__ wfI,
    float* __restrict__ biasf, float* __restrict__ l0w, float* __restrict__ l0b)
{
  int idx = blockIdx.x * 256 + threadIdx.x;
  if (idx < 153600) {                        // wfA [3][25][4][64][8]
    int l = idx / 51200, r = idx % 51200;
    int nt = r / 2048, r2 = r % 2048;
    int kt = r2 / 512, r3 = r2 % 512;
    int lane = r3 / 8, j = r3 % 8;
    int mp = nt * 16 + (lane & 15);
    int grow = (mp & 3) * HH + (mp >> 2);
    int k = kt * 32 + (lane >> 4) * 8 + j;
    const float* Wm = (l == 0) ? Whh0 : ((l == 1) ? Whh1 : Whh2);
    wfA[idx] = (k < HH) ? (f16)Wm[grow * HH + k] : (f16)0.0f;
    return;
  }
  idx -= 153600;
  if (idx < 102400) {                        // wfI [2][25][4][64][8]
    int l = idx / 51200, r = idx % 51200;
    int nt = r / 2048, r2 = r % 2048;
    int kt = r2 / 512, r3 = r2 % 512;
    int lane = r3 / 8, j = r3 % 8;
    int mp = nt * 16 + (lane & 15);
    int grow = (mp & 3) * HH + (mp >> 2);
    int k = kt * 32 + (lane >> 4) * 8 + j;
    const float* Wm = (l == 0) ? Wih1 : Wih2;
    wfI[idx] = (k < HH) ? (f16)Wm[grow * HH + k] : (f16)0.0f;
    return;
  }
  idx -= 102400;
  if (idx < 12800) {                         // biasf [2][25][64][4]
    int l = idx / 6400, r = idx % 6400;
    int nt = r / 256, r2 = r % 256;
    int lane = r2 / 4, rr = r2 % 4;
    int mp = nt * 16 + (lane >> 4) * 4 + rr;
    int grow = (mp & 3) * HH + (mp >> 2);
    biasf[idx] = ((l == 0) ? b1 : b2)[grow];
    return;
  }
  idx -= 12800;
  if (idx < 12800) {                         // l0w / l0b [25][64][4]
    int w = idx / 6400, r = idx % 6400;
    int nt = r / 256, r2 = r % 256;
    int lane = r2 / 4, rr = r2 % 4;
    int mp = nt * 16 + (lane >> 4) * 4 + rr;
    int grow = (mp & 3) * HH + (mp >> 2);
    if (w == 0) l0w[r] = Wih0[grow];
    else        l0b[r] = b0[grow];
  }
}

// ---------------- fused 3-layer pipelined recurrence ----------------
__global__ PIN22 void lstm3(
    const float* __restrict__ z,       // [NB][NT]
    const float* __restrict__ l0w,     // [25][64][4]
    const float* __restrict__ l0b,
    const f16* __restrict__ wfA,       // [3][25][4][64][8]
    const f16* __restrict__ wfI,       // [2][25][4][64][8]
    const float* __restrict__ biasf,   // [2][25][64][4]
    f16* __restrict__ ring,            // [2][NBG][RW][16][XROW] f16
    float* __restrict__ hbufT,         // [NBG][NT][HH][16] f32 (layer2 out)
    uint32_t* __restrict__ prodc,      // [2][NBG][16] u32
    uint32_t* __restrict__ consc)      // [2][NBG][16] u32
{
  const int tid = threadIdx.x;
  const int w = tid >> 6, lane = tid & 63;
  const int layer = blockIdx.x >> 5;         // 0,1,2
  const int bg = blockIdx.x & 31;
  const int br = lane & 15, lg = lane >> 4;
  const int NS = (w == 0) ? 4 : 3;           // slots: nt = w + 8*s

  __shared__ __align__(16) f16 hHi[2][16 * KP];
  __shared__ __align__(16) f16 hLo[2][16 * KP];
  __shared__ __align__(16) float zl[NT][16];   // layer0 only

  {
    uint32_t* p0 = (uint32_t*)&hHi[0][0];
    uint32_t* p1 = (uint32_t*)&hLo[0][0];
    for (int i = tid; i < 2 * 16 * KP / 2; i += 512) { p0[i] = 0u; p1[i] = 0u; }
  }
  if (layer == 0) {
    for (int i = tid; i < 16 * NT; i += 512) {
      int j = i / NT, t = i % NT;
      zl[t][j] = z[(size_t)(bg * 16 + j) * NT + t];
    }
  }

  // per-layer tables
  const f16* wfAl = wfA + (size_t)layer * 51200;
  f16x8 A[4][4], AI[4][4];
  f32x4 wv[4], bv[4], bias4[4];
  float c[4] = {0.f, 0.f, 0.f, 0.f};
#pragma unroll
  for (int s = 0; s < 4; ++s) {
    if (s < NS) {
      const int nt = w + 8 * s;
#pragma unroll
      for (int kt = 0; kt < 4; ++kt)
        A[s][kt] = *(const f16x8*)(wfAl + ((nt * 4 + kt) * 64 + lane) * 8);
      if (layer == 0) {
        wv[s] = *(const f32x4*)(l0w + (nt * 64 + lane) * 4);
        bv[s] = *(const f32x4*)(l0b + (nt * 64 + lane) * 4);
      } else {
        const f16* wfIl = wfI + (size_t)(layer - 1) * 51200;
#pragma unroll
        for (int kt = 0; kt < 4; ++kt)
          AI[s][kt] = *(const f16x8*)(wfIl + ((nt * 4 + kt) * 64 + lane) * 8);
        bias4[s] = *(const f32x4*)(biasf + (size_t)(layer - 1) * 6400 + (nt * 64 + lane) * 4);
      }
    }
  }

  // pipeline plumbing
  uint32_t* myProd = prodc + ((size_t)layer * NBG + bg) * 16;        // layer<2
  uint32_t* myCons = consc + ((size_t)layer * NBG + bg) * 16;        // layer<2
  const uint32_t* upProd = prodc + ((size_t)(layer - 1) * NBG + bg) * 16;
  uint32_t* upCons = consc + ((size_t)(layer - 1) * NBG + bg) * 16;
  f16* myPipe = ring + ((size_t)layer * NBG + bg) * RW * 16 * XROW;  // layer<2
  const f16* srcPipe = ring + ((size_t)(layer - 1) * NBG + bg) * RW * 16 * XROW;

  // consumer prologue: x(0) fragments
  f16x8 Bx[4];
  if (layer >= 1) {
    spin_ge(upProd, 1u);
#pragma unroll
    for (int kt = 0; kt < 4; ++kt)
      Bx[kt] = *(const f16x8*)(srcPipe + br * XROW + kt * 32 + lg * 8);
  }
  __syncthreads();

  int cur = 0;
  for (int t = 0; t < NT; ++t) {
    // 1. LDS h fragments (latency overlapped by ax chains below)
    f16x8 Bhi[4], Blo[4];
#pragma unroll
    for (int kt = 0; kt < 4; ++kt) {
      const int pos = bswz(br, (kt << 2) + lg);
      Bhi[kt] = *(const f16x8*)(&hHi[cur][pos]);
      Blo[kt] = *(const f16x8*)(&hLo[cur][pos]);
    }
    // 2. ax = Wih . x(t)  (reg-only MFMA chains; consumes Bx)
    f32x4 ax[4];
    if (layer >= 1) {
#pragma unroll
      for (int s = 0; s < 4; ++s) {
        if (s < NS) {
          f32x4 a = {0.f, 0.f, 0.f, 0.f};
#pragma unroll
          for (int kt = 0; kt < 4; ++kt)
            a = __builtin_amdgcn_mfma_f32_16x16x32_f16(AI[s][kt], Bx[kt], a, 0, 0, 0);
          ax[s] = a;
        }
      }
      // 3. Bx regs free: prefetch x(t+1) (hidden under rest of step)
      if (t + 1 < NT) {
        spin_ge(upProd, (uint32_t)(t + 2));
        const f16* sb = srcPipe + (size_t)((t + 1) & (RW - 1)) * 16 * XROW;
#pragma unroll
        for (int kt = 0; kt < 4; ++kt)
          Bx[kt] = *(const f16x8*)(sb + br * XROW + kt * 32 + lg * 8);
      }
    }
    // 4. producer throttle: don't overwrite ring slot t%RW too early
    if (layer < 2 && t >= RW) spin_ge(myCons, (uint32_t)(t - RW + 1));

    // 5. recurrent chains + activation + state update + publish
#pragma unroll
    for (int s = 0; s < 4; ++s) {
      if (s < NS) {
        const int nt = w + 8 * s;
        f32x4 ah = (layer == 0) ? (bv[s] + wv[s] * zl[t][br]) : bias4[s];
        f32x4 al = {0.f, 0.f, 0.f, 0.f};
#pragma unroll
        for (int kt = 0; kt < 4; ++kt) {
          ah = __builtin_amdgcn_mfma_f32_16x16x32_f16(A[s][kt], Bhi[kt], ah, 0, 0, 0);
          al = __builtin_amdgcn_mfma_f32_16x16x32_f16(A[s][kt], Blo[kt], al, 0, 0, 0);
        }
        f32x4 acc = ah + al;
        if (layer >= 1) acc = acc + ax[s];
        float iv = sigm(acc.x);
        float fv = sigm(acc.y);
        float gv = tanh_(acc.z);
        float ov = sigm(acc.w);
        c[s] = fv * c[s] + iv * gv;
        float hv = ov * tanh_(c[s]);
        const int u = nt * 4 + lg;
        if (layer < 2) {
          myPipe[(size_t)(t & (RW - 1)) * 16 * XROW + br * XROW + u] = (f16)hv;
        } else {
          hbufT[(((size_t)bg * NT + t) * HH + u) * 16 + br] = hv;
        }
        f16 hi = (f16)hv;
        hHi[cur ^ 1][hswz(br, u)] = hi;
        hLo[cur ^ 1][hswz(br, u)] = (f16)(hv - (float)hi);
      }
    }
    __syncthreads();   // drains all waves' vmem (publish stores in L2)
    if (tid == 0) {
      if (layer < 2) rel_store(myProd, (uint32_t)(t + 1));   // flush + signal
      if (layer >= 1) rel_store(upCons, (uint32_t)(t + 1));  // backpressure
    }
    cur ^= 1;
  }
}

// ---------------- projection ----------------
__global__ __launch_bounds__(256) void proj(
    const float* __restrict__ hbufT,
    const float* __restrict__ Wp, const float* __restrict__ bp,
    float* __restrict__ out)
{
  const int tid = threadIdx.x;
  const int bg = blockIdx.x >> 5, tsub = blockIdx.x & 31;
  const int br = tid & 15, tl = tid >> 4;
  const int t = tsub * 16 + tl;
  const float* hp = hbufT + (((size_t)bg * NT + t) * HH) * 16 + br;
  float acc = 0.0f;
#pragma unroll 4
  for (int u = 0; u < HH; ++u) acc += hp[u * 16] * Wp[u];
  out[(size_t)(bg * 16 + br) * NT + t] = tanh_(acc + bp[0]);
}

extern "C" void kernel_launch(void* const* d_in, const int* in_sizes, int n_in,
                              void* d_out, int out_size, void* d_ws, size_t ws_size,
                              hipStream_t stream) {
  const float* z    = (const float*)d_in[0];
  const float* Wih0 = (const float*)d_in[1];
  const float* Whh0 = (const float*)d_in[2];
  const float* b0   = (const float*)d_in[3];
  const float* Wih1 = (const float*)d_in[4];
  const float* Whh1 = (const float*)d_in[5];
  const float* b1   = (const float*)d_in[6];
  const float* Wih2 = (const float*)d_in[7];
  const float* Whh2 = (const float*)d_in[8];
  const float* b2   = (const float*)d_in[9];
  const float* Wp   = (const float*)d_in[10];
  const float* bp   = (const float*)d_in[11];
  float* out = (float*)d_out;

  float* ws = (float*)d_ws;
  float*    hbufT = ws;                               // 26,214,400 f32
  f16*      ring  = (f16*)(ws + 26214400);            // 2*32*16*16*104 f16 = 851,968 f32
  uint32_t* prodc = (uint32_t*)(ws + 26214400 + 851968);        // 1024 u32
  uint32_t* consc = prodc + 1024;                               // 1024 u32
  f16*      wfA   = (f16*)(ws + 26214400 + 851968 + 2048);      // 153,600 f16
  f16*      wfI   = wfA + 153600;                               // 102,400 f16
  float*    biasf = (float*)(wfI + 102400);                     // 12,800 f32
  float*    l0w   = biasf + 12800;                              // 6,400
  float*    l0b   = l0w + 6400;                                 // 6,400

  initk<<<2048, 256, 0, stream>>>((uint32_t*)ring, prodc);
  wprep<<<1100, 256, 0, stream>>>(Whh0, Whh1, Whh2, Wih1, Wih2, b1, b2,
                                  Wih0, b0, wfA, wfI, biasf, l0w, l0b);
  lstm3<<<96, 512, 0, stream>>>(z, l0w, l0b, wfA, wfI, biasf,
                                ring, hbufT, prodc, consc);
  proj<<<1024, 256, 0, stream>>>(hbufT, Wp, bp, out);
}